// Round 1
// baseline (1191.775 us; speedup 1.0000x reference)
//
#include <hip/hip_runtime.h>
#include <cstdint>
#include <cstddef>

#define NNODES 100000
#define NEDGES 1000000
#define HDIM 64

__device__ __forceinline__ void fma4(float4& acc, const float4 a, const float4 b) {
    acc.x = fmaf(a.x, b.x, acc.x);
    acc.y = fmaf(a.y, b.y, acc.y);
    acc.z = fmaf(a.z, b.z, acc.z);
    acc.w = fmaf(a.w, b.w, acc.w);
}

// agg[src[e]] += h[dst[e]] for edges with edge_type == rel.
// One wave per edge; lane = channel. Coalesced 256B/512B row bursts.
template<int K>
__global__ __launch_bounds__(256) void scatter_kernel(
    const int* __restrict__ srcv, const int* __restrict__ dstv,
    const int* __restrict__ ety, const float* __restrict__ h,
    float* __restrict__ agg, int rel, int nEdges)
{
    const int lane = threadIdx.x & 63;
    const int wid  = (int)((blockIdx.x * blockDim.x + threadIdx.x) >> 6);
    const int nw   = (int)((gridDim.x * blockDim.x) >> 6);
    for (int e = wid; e < nEdges; e += nw) {
        if (ety[e] != rel) continue;          // wave-uniform branch
        const int s = srcv[e];
        const int d = dstv[e];
        const float* hr = h + (size_t)d * K;
        float* ar = agg + (size_t)s * K;
        #pragma unroll
        for (int j = 0; j < K / 64; ++j) {
            const float v = hr[lane + j * 64];
            if (v != 0.0f) atomicAdd(&ar[lane + j * 64], v);  // skip relu zeros
        }
    }
}

// out[n][o] = relu( sum_k A1[n][k]*W1[o][k] + A2[n][k]*(W2a+W2b)[o][k] + bias[o] )
// lane = o. Weights held in VGPRs (128 regs/lane). Input rows are wave-uniform
// broadcast loads. SPLIT (K=128): wave pairs split k; tiny LDS reduction.
template<int K, bool SPLIT>
__global__ __launch_bounds__(256) void dense_kernel(
    const float* __restrict__ A1, const float* __restrict__ A2,
    const float* __restrict__ W1, const float* __restrict__ W2a, const float* __restrict__ W2b,
    const float* __restrict__ B1, const float* __restrict__ B2, const float* __restrict__ B3,
    float* __restrict__ out, int nNodes)
{
    const int lane  = threadIdx.x & 63;
    const int wave  = threadIdx.x >> 6;
    const int khalf = SPLIT ? (wave & 1) : 0;
    const int group = SPLIT ? (wave >> 1) : wave;
    const int kbase = khalf * 64;

    // Stage this lane's weight rows (k-chunk of 64) into registers.
    float4 w1q[16], w2q[16];
    const float* w1row  = W1  + (size_t)lane * K + kbase;
    const float* w2arow = W2a + (size_t)lane * K + kbase;
    const float* w2brow = W2b + (size_t)lane * K + kbase;
    #pragma unroll
    for (int j = 0; j < 16; ++j) {
        w1q[j] = *(const float4*)(w1row + j * 4);
        const float4 a = *(const float4*)(w2arow + j * 4);
        const float4 b = *(const float4*)(w2brow + j * 4);
        w2q[j] = make_float4(a.x + b.x, a.y + b.y, a.z + b.z, a.w + b.w);
    }
    const float bias = B1[lane] + B2[lane] + B3[lane];

    __shared__ float red[2][64];

    const int gpb    = SPLIT ? 2 : 4;  // node-groups per block
    const int stride = (int)gridDim.x * gpb;

    if constexpr (SPLIT) {
        const int iters = (nNodes + stride - 1) / stride;
        int n = (int)blockIdx.x * gpb + group;
        for (int it = 0; it < iters; ++it, n += stride) {
            float p = 0.0f;
            if (n < nNodes) {
                const float4* a1p = (const float4*)(A1 + (size_t)n * K + kbase);
                const float4* a2p = (const float4*)(A2 + (size_t)n * K + kbase);
                float4 s1 = make_float4(0, 0, 0, 0), s2 = make_float4(0, 0, 0, 0);
                #pragma unroll
                for (int j = 0; j < 16; ++j) { fma4(s1, a1p[j], w1q[j]); fma4(s2, a2p[j], w2q[j]); }
                p = (s1.x + s1.y + s1.z + s1.w) + (s2.x + s2.y + s2.z + s2.w);
            }
            if (khalf == 1) red[group][lane] = p;
            __syncthreads();
            if (khalf == 0 && n < nNodes) {
                const float r = p + red[group][lane] + bias;
                out[(size_t)n * 64 + lane] = r > 0.0f ? r : 0.0f;
            }
            __syncthreads();
        }
    } else {
        for (int n = (int)blockIdx.x * gpb + group; n < nNodes; n += stride) {
            const float4* a1p = (const float4*)(A1 + (size_t)n * K);
            const float4* a2p = (const float4*)(A2 + (size_t)n * K);
            float4 s1 = make_float4(0, 0, 0, 0), s2 = make_float4(0, 0, 0, 0);
            #pragma unroll
            for (int j = 0; j < 16; ++j) { fma4(s1, a1p[j], w1q[j]); fma4(s2, a2p[j], w2q[j]); }
            float r = (s1.x + s1.y + s1.z + s1.w) + (s2.x + s2.y + s2.z + s2.w) + bias;
            out[(size_t)n * 64 + lane] = r > 0.0f ? r : 0.0f;
        }
    }
}

extern "C" void kernel_launch(void* const* d_in, const int* in_sizes, int n_in,
                              void* d_out, int out_size, void* d_ws, size_t ws_size,
                              hipStream_t stream)
{
    const float* x    = (const float*)d_in[0];
    const int*   eidx = (const int*)d_in[1];
    const int*   ety  = (const int*)d_in[2];
    const int*   srcv = eidx;            // edge_index[0]
    const int*   dstv = eidx + NEDGES;   // edge_index[1]

    const float* wl0 = (const float*)d_in[3];
    const float* bl0 = (const float*)d_in[4];
    const float* w00 = (const float*)d_in[5];
    const float* b00 = (const float*)d_in[6];
    const float* w10 = (const float*)d_in[7];
    const float* b10 = (const float*)d_in[8];

    const float* wl1 = (const float*)d_in[9];
    const float* bl1 = (const float*)d_in[10];
    const float* w01 = (const float*)d_in[11];
    const float* b01 = (const float*)d_in[12];
    const float* w11 = (const float*)d_in[13];
    const float* b11 = (const float*)d_in[14];

    const float* wl2 = (const float*)d_in[15];
    const float* bl2 = (const float*)d_in[16];
    const float* w02 = (const float*)d_in[17];
    const float* b02 = (const float*)d_in[18];
    const float* w12 = (const float*)d_in[19];
    const float* b12 = (const float*)d_in[20];

    float* agg = (float*)d_ws;                                             // [N,128] max, 51.2 MB
    float* h2  = (float*)((char*)d_ws + (size_t)NNODES * 128 * sizeof(float)); // [N,64], 25.6 MB
    float* h1  = (float*)d_out;                                            // reuse d_out as h1

    // ---- Layer 0: K = 128 (h = x, x_in = x) ----
    hipMemsetAsync(agg, 0, (size_t)NNODES * 128 * sizeof(float), stream);
    scatter_kernel<128><<<4096, 256, 0, stream>>>(srcv, dstv, ety, x, agg, 0, NEDGES);
    dense_kernel<128, true><<<2048, 256, 0, stream>>>(agg, x, wl0, w00, w10,
                                                      bl0, b00, b10, h1, NNODES);

    // ---- Layer 1: K = 64 ----
    hipMemsetAsync(agg, 0, (size_t)NNODES * 64 * sizeof(float), stream);
    scatter_kernel<64><<<4096, 256, 0, stream>>>(srcv, dstv, ety, h1, agg, 1, NEDGES);
    dense_kernel<64, false><<<2048, 256, 0, stream>>>(agg, h1, wl1, w01, w11,
                                                      bl1, b01, b11, h2, NNODES);

    // ---- Layer 2: K = 64 (write final output; h1's storage no longer needed) ----
    hipMemsetAsync(agg, 0, (size_t)NNODES * 64 * sizeof(float), stream);
    scatter_kernel<64><<<4096, 256, 0, stream>>>(srcv, dstv, ety, h2, agg, 2, NEDGES);
    dense_kernel<64, false><<<2048, 256, 0, stream>>>(agg, h2, wl2, w02, w12,
                                                      bl2, b02, b12, (float*)d_out, NNODES);
}

// Round 2
// 635.056 us; speedup vs baseline: 1.8766x; 1.8766x over previous
//
#include <hip/hip_runtime.h>
#include <cstdint>
#include <cstddef>

#define NNODES 100000
#define NEDGES 1000000
#define HDIM 64

// agg[src[e]] += h[dst[e]] for edges with edge_type == rel.
// One wave per edge; lane = channel. Coalesced 256B/512B row bursts.
template<int K>
__global__ __launch_bounds__(256) void scatter_kernel(
    const int* __restrict__ srcv, const int* __restrict__ dstv,
    const int* __restrict__ ety, const float* __restrict__ h,
    float* __restrict__ agg, int rel, int nEdges)
{
    const int lane = threadIdx.x & 63;
    const int wid  = (int)((blockIdx.x * blockDim.x + threadIdx.x) >> 6);
    const int nw   = (int)((gridDim.x * blockDim.x) >> 6);
    for (int e = wid; e < nEdges; e += nw) {
        if (ety[e] != rel) continue;          // wave-uniform branch
        const int s = srcv[e];
        const int d = dstv[e];
        const float* hr = h + (size_t)d * K;
        float* ar = agg + (size_t)s * K;
        #pragma unroll
        for (int j = 0; j < K / 64; ++j) {
            const float v = hr[lane + j * 64];
            if (v != 0.0f) atomicAdd(&ar[lane + j * 64], v);  // skip relu zeros
        }
    }
}

// out = relu( A1 @ W1^T + A2 @ (W2a+W2b)^T + (B1+B2+B3) )
// Register-tiled GEMM: block = 64 nodes x 64 outs, 256 threads, 4x4 acc/thread.
// A and W chunks staged k-major in LDS ([k][n] / [k][o]) so the inner loop is
// 2 x ds_read_b128 (A broadcast across tx; W 2-way across lanes) per 16 FMAs.
template<int K>
__global__ __launch_bounds__(256) void dense_gemm(
    const float* __restrict__ A1, const float* __restrict__ A2,
    const float* __restrict__ W1, const float* __restrict__ W2a, const float* __restrict__ W2b,
    const float* __restrict__ B1, const float* __restrict__ B2, const float* __restrict__ B3,
    float* __restrict__ out, int nNodes)
{
    __shared__ float As[16][64];
    __shared__ float Ws[16][64];

    const int t  = (int)threadIdx.x;
    const int tx = t & 15;        // output-group (4 outs)
    const int ty = t >> 4;        // node-group (4 nodes)
    const int n0 = (int)blockIdx.x * 64;

    const int srow = t >> 2;          // staging row index (node or out), 0..63
    const int skk  = (t & 3) * 4;     // staging k offset within 16-chunk

    float4 acc[4];
    #pragma unroll
    for (int i = 0; i < 4; ++i) acc[i] = make_float4(0.f, 0.f, 0.f, 0.f);

    const int KC = K / 16;            // 16-wide k-chunks per matrix
    const int nA = n0 + srow;

    #pragma unroll 1
    for (int c = 0; c < 2 * KC; ++c) {
        const bool first = (c < KC);
        const int k0 = (first ? c : c - KC) * 16;

        // --- coalesced global loads for this chunk ---
        float4 av = make_float4(0.f, 0.f, 0.f, 0.f);
        if (nA < nNodes) {
            const float* Ab = first ? A1 : A2;
            av = *(const float4*)(Ab + (size_t)nA * K + k0 + skk);
        }
        float4 wv;
        if (first) {
            wv = *(const float4*)(W1 + (size_t)srow * K + k0 + skk);
        } else {
            const float4 a = *(const float4*)(W2a + (size_t)srow * K + k0 + skk);
            const float4 b = *(const float4*)(W2b + (size_t)srow * K + k0 + skk);
            wv = make_float4(a.x + b.x, a.y + b.y, a.z + b.z, a.w + b.w);
        }

        __syncthreads();   // previous chunk fully consumed
        As[skk + 0][srow] = av.x; As[skk + 1][srow] = av.y;
        As[skk + 2][srow] = av.z; As[skk + 3][srow] = av.w;
        Ws[skk + 0][srow] = wv.x; Ws[skk + 1][srow] = wv.y;
        Ws[skk + 2][srow] = wv.z; Ws[skk + 3][srow] = wv.w;
        __syncthreads();

        // --- compute ---
        #pragma unroll
        for (int k = 0; k < 16; ++k) {
            const float4 a4 = *(const float4*)&As[k][ty * 4];
            const float4 w4 = *(const float4*)&Ws[k][tx * 4];
            acc[0].x = fmaf(a4.x, w4.x, acc[0].x); acc[0].y = fmaf(a4.x, w4.y, acc[0].y);
            acc[0].z = fmaf(a4.x, w4.z, acc[0].z); acc[0].w = fmaf(a4.x, w4.w, acc[0].w);
            acc[1].x = fmaf(a4.y, w4.x, acc[1].x); acc[1].y = fmaf(a4.y, w4.y, acc[1].y);
            acc[1].z = fmaf(a4.y, w4.z, acc[1].z); acc[1].w = fmaf(a4.y, w4.w, acc[1].w);
            acc[2].x = fmaf(a4.z, w4.x, acc[2].x); acc[2].y = fmaf(a4.z, w4.y, acc[2].y);
            acc[2].z = fmaf(a4.z, w4.z, acc[2].z); acc[2].w = fmaf(a4.z, w4.w, acc[2].w);
            acc[3].x = fmaf(a4.w, w4.x, acc[3].x); acc[3].y = fmaf(a4.w, w4.y, acc[3].y);
            acc[3].z = fmaf(a4.w, w4.z, acc[3].z); acc[3].w = fmaf(a4.w, w4.w, acc[3].w);
        }
    }

    // --- epilogue: bias + relu + coalesced float4 store ---
    const float4 b1 = *(const float4*)(B1 + tx * 4);
    const float4 b2 = *(const float4*)(B2 + tx * 4);
    const float4 b3 = *(const float4*)(B3 + tx * 4);
    const float4 bias = make_float4(b1.x + b2.x + b3.x, b1.y + b2.y + b3.y,
                                    b1.z + b2.z + b3.z, b1.w + b2.w + b3.w);
    #pragma unroll
    for (int i = 0; i < 4; ++i) {
        const int n = n0 + ty * 4 + i;
        if (n < nNodes) {
            float4 r = make_float4(acc[i].x + bias.x, acc[i].y + bias.y,
                                   acc[i].z + bias.z, acc[i].w + bias.w);
            r.x = r.x > 0.f ? r.x : 0.f;
            r.y = r.y > 0.f ? r.y : 0.f;
            r.z = r.z > 0.f ? r.z : 0.f;
            r.w = r.w > 0.f ? r.w : 0.f;
            *(float4*)(out + (size_t)n * 64 + tx * 4) = r;
        }
    }
}

extern "C" void kernel_launch(void* const* d_in, const int* in_sizes, int n_in,
                              void* d_out, int out_size, void* d_ws, size_t ws_size,
                              hipStream_t stream)
{
    const float* x    = (const float*)d_in[0];
    const int*   eidx = (const int*)d_in[1];
    const int*   ety  = (const int*)d_in[2];
    const int*   srcv = eidx;            // edge_index[0]
    const int*   dstv = eidx + NEDGES;   // edge_index[1]

    const float* wl0 = (const float*)d_in[3];
    const float* bl0 = (const float*)d_in[4];
    const float* w00 = (const float*)d_in[5];
    const float* b00 = (const float*)d_in[6];
    const float* w10 = (const float*)d_in[7];
    const float* b10 = (const float*)d_in[8];

    const float* wl1 = (const float*)d_in[9];
    const float* bl1 = (const float*)d_in[10];
    const float* w01 = (const float*)d_in[11];
    const float* b01 = (const float*)d_in[12];
    const float* w11 = (const float*)d_in[13];
    const float* b11 = (const float*)d_in[14];

    const float* wl2 = (const float*)d_in[15];
    const float* bl2 = (const float*)d_in[16];
    const float* w02 = (const float*)d_in[17];
    const float* b02 = (const float*)d_in[18];
    const float* w12 = (const float*)d_in[19];
    const float* b12 = (const float*)d_in[20];

    float* agg = (float*)d_ws;                                                  // [N,128] max
    float* h2  = (float*)((char*)d_ws + (size_t)NNODES * 128 * sizeof(float));  // [N,64]
    float* h1  = (float*)d_out;                                                 // reuse d_out as h1

    const int gemmGrid = (NNODES + 63) / 64;

    // ---- Layer 0: K = 128 (h = x = x_in) ----
    hipMemsetAsync(agg, 0, (size_t)NNODES * 128 * sizeof(float), stream);
    scatter_kernel<128><<<4096, 256, 0, stream>>>(srcv, dstv, ety, x, agg, 0, NEDGES);
    dense_gemm<128><<<gemmGrid, 256, 0, stream>>>(agg, x, wl0, w00, w10,
                                                  bl0, b00, b10, h1, NNODES);

    // ---- Layer 1: K = 64 ----
    hipMemsetAsync(agg, 0, (size_t)NNODES * 64 * sizeof(float), stream);
    scatter_kernel<64><<<4096, 256, 0, stream>>>(srcv, dstv, ety, h1, agg, 1, NEDGES);
    dense_gemm<64><<<gemmGrid, 256, 0, stream>>>(agg, h1, wl1, w01, w11,
                                                 bl1, b01, b11, h2, NNODES);

    // ---- Layer 2: K = 64 (final output) ----
    hipMemsetAsync(agg, 0, (size_t)NNODES * 64 * sizeof(float), stream);
    scatter_kernel<64><<<4096, 256, 0, stream>>>(srcv, dstv, ety, h2, agg, 2, NEDGES);
    dense_gemm<64><<<gemmGrid, 256, 0, stream>>>(agg, h2, wl2, w02, w12,
                                                 bl2, b02, b12, (float*)d_out, NNODES);
}

// Round 4
// 501.086 us; speedup vs baseline: 2.3784x; 1.2674x over previous
//
#include <hip/hip_runtime.h>
#include <cstdint>
#include <cstddef>

#define NNODES 100000
#define NEDGES 1000000
#define NREL 3
#define RN (NREL * NNODES)
#define EPB 2048                       // elements per scan block (256 thr x 8)
#define SCAN_BLOCKS ((RN + EPB - 1) / EPB)   // 147

// ---------------- CSR build ----------------

__global__ __launch_bounds__(256) void hist_kernel(
    const int* __restrict__ srcv, const int* __restrict__ ety, int* __restrict__ cnt)
{
    const int e = (int)(blockIdx.x * 256 + threadIdx.x);
    if (e < NEDGES) atomicAdd(&cnt[ety[e] * NNODES + srcv[e]], 1);
}

__global__ __launch_bounds__(256) void scan_reduce(
    const int* __restrict__ cnt, int* __restrict__ bsum)
{
    __shared__ int sd[256];
    const int t = (int)threadIdx.x;
    const int base = (int)blockIdx.x * EPB + t * 8;
    int s = 0;
    #pragma unroll
    for (int i = 0; i < 8; ++i)
        if (base + i < RN) s += cnt[base + i];
    sd[t] = s;
    __syncthreads();
    for (int st = 128; st > 0; st >>= 1) {
        if (t < st) sd[t] += sd[t + st];
        __syncthreads();
    }
    if (t == 0) bsum[blockIdx.x] = sd[0];
}

__global__ __launch_bounds__(256) void scan_blocksums(int* __restrict__ bsum, int nb)
{
    __shared__ int buf0[256], buf1[256];
    const int t = (int)threadIdx.x;
    buf0[t] = (t < nb) ? bsum[t] : 0;
    __syncthreads();
    int* a = buf0; int* b = buf1;
    for (int st = 1; st < 256; st <<= 1) {
        int v = a[t];
        if (t >= st) v += a[t - st];
        b[t] = v;
        __syncthreads();
        int* tmp = a; a = b; b = tmp;
    }
    if (t < nb) bsum[t] = (t == 0) ? 0 : a[t - 1];   // exclusive
}

__global__ __launch_bounds__(256) void scan_final(
    const int* __restrict__ cnt, const int* __restrict__ bsum,
    int* __restrict__ off, int* __restrict__ wptr)
{
    __shared__ int buf0[256], buf1[256];
    const int t = (int)threadIdx.x;
    const int base = (int)blockIdx.x * EPB + t * 8;
    int v[8];
    int tot = 0;
    #pragma unroll
    for (int i = 0; i < 8; ++i) {
        v[i] = (base + i < RN) ? cnt[base + i] : 0;
        tot += v[i];
    }
    buf0[t] = tot;
    __syncthreads();
    int* a = buf0; int* b = buf1;
    for (int st = 1; st < 256; st <<= 1) {
        int s = a[t];
        if (t >= st) s += a[t - st];
        b[t] = s;
        __syncthreads();
        int* tmp = a; a = b; b = tmp;
    }
    int o = bsum[blockIdx.x] + ((t == 0) ? 0 : a[t - 1]);
    #pragma unroll
    for (int i = 0; i < 8; ++i) {
        if (base + i < RN) { off[base + i] = o; wptr[base + i] = o; }
        o += v[i];
    }
    if (blockIdx.x == 0 && t == 0) off[RN] = NEDGES;
}

__global__ __launch_bounds__(256) void fill_kernel(
    const int* __restrict__ srcv, const int* __restrict__ dstv,
    const int* __restrict__ ety, int* __restrict__ wptr, int* __restrict__ ebuf)
{
    const int e = (int)(blockIdx.x * 256 + threadIdx.x);
    if (e < NEDGES) {
        const int pos = atomicAdd(&wptr[ety[e] * NNODES + srcv[e]], 1);
        ebuf[pos] = dstv[e];
    }
}

// ---------------- gather: agg[n][:] = sum over edges (rel,n) of h[dst][:] ----------------
// One wave per node, lane = channel. Coalesced 256B row gathers (h is L3-resident),
// one streaming row write. No atomics, no memset needed.
template<int K>
__global__ __launch_bounds__(256) void gather_kernel(
    const int* __restrict__ off, const int* __restrict__ ebuf,
    const float* __restrict__ h, float* __restrict__ agg, int rel)
{
    const int lane = (int)(threadIdx.x & 63);
    const int wid  = (int)((blockIdx.x * blockDim.x + threadIdx.x) >> 6);
    const int nw   = (int)((gridDim.x * blockDim.x) >> 6);
    const int* o = off + rel * NNODES;
    for (int n = wid; n < NNODES; n += nw) {
        const int s  = o[n];
        const int e1 = o[n + 1];
        float a0 = 0.f, a1 = 0.f;
        for (int j = s; j < e1; ++j) {
            const int d = ebuf[j];
            const float* hr = h + (size_t)d * K;
            a0 += hr[lane];
            if (K == 128) a1 += hr[64 + lane];
        }
        agg[(size_t)n * K + lane] = a0;
        if (K == 128) agg[(size_t)n * K + 64 + lane] = a1;
    }
}

// ---------------- dense: out = relu( A1 @ W1^T + A2 @ (W2a+W2b)^T + biases ) ----------------
template<int K>
__global__ __launch_bounds__(256) void dense_gemm(
    const float* __restrict__ A1, const float* __restrict__ A2,
    const float* __restrict__ W1, const float* __restrict__ W2a, const float* __restrict__ W2b,
    const float* __restrict__ B1, const float* __restrict__ B2, const float* __restrict__ B3,
    float* __restrict__ out, int nNodes)
{
    __shared__ float As[16][64];
    __shared__ float Ws[16][64];

    const int t  = (int)threadIdx.x;
    const int tx = t & 15;        // output-group (4 outs)
    const int ty = t >> 4;        // node-group (4 nodes)
    const int n0 = (int)blockIdx.x * 64;

    const int srow = t >> 2;          // staging row index (node or out), 0..63
    const int skk  = (t & 3) * 4;     // staging k offset within 16-chunk

    float4 acc[4];
    #pragma unroll
    for (int i = 0; i < 4; ++i) acc[i] = make_float4(0.f, 0.f, 0.f, 0.f);

    const int KC = K / 16;            // 16-wide k-chunks per matrix
    const int nA = n0 + srow;

    #pragma unroll 1
    for (int c = 0; c < 2 * KC; ++c) {
        const bool first = (c < KC);
        const int k0 = (first ? c : c - KC) * 16;

        float4 av = make_float4(0.f, 0.f, 0.f, 0.f);
        if (nA < nNodes) {
            const float* Ab = first ? A1 : A2;
            av = *(const float4*)(Ab + (size_t)nA * K + k0 + skk);
        }
        float4 wv;
        if (first) {
            wv = *(const float4*)(W1 + (size_t)srow * K + k0 + skk);
        } else {
            const float4 a = *(const float4*)(W2a + (size_t)srow * K + k0 + skk);
            const float4 b = *(const float4*)(W2b + (size_t)srow * K + k0 + skk);
            wv = make_float4(a.x + b.x, a.y + b.y, a.z + b.z, a.w + b.w);
        }

        __syncthreads();
        As[skk + 0][srow] = av.x; As[skk + 1][srow] = av.y;
        As[skk + 2][srow] = av.z; As[skk + 3][srow] = av.w;
        Ws[skk + 0][srow] = wv.x; Ws[skk + 1][srow] = wv.y;
        Ws[skk + 2][srow] = wv.z; Ws[skk + 3][srow] = wv.w;
        __syncthreads();

        #pragma unroll
        for (int k = 0; k < 16; ++k) {
            const float4 a4 = *(const float4*)&As[k][ty * 4];
            const float4 w4 = *(const float4*)&Ws[k][tx * 4];
            acc[0].x = fmaf(a4.x, w4.x, acc[0].x); acc[0].y = fmaf(a4.x, w4.y, acc[0].y);
            acc[0].z = fmaf(a4.x, w4.z, acc[0].z); acc[0].w = fmaf(a4.x, w4.w, acc[0].w);
            acc[1].x = fmaf(a4.y, w4.x, acc[1].x); acc[1].y = fmaf(a4.y, w4.y, acc[1].y);
            acc[1].z = fmaf(a4.y, w4.z, acc[1].z); acc[1].w = fmaf(a4.y, w4.w, acc[1].w);
            acc[2].x = fmaf(a4.z, w4.x, acc[2].x); acc[2].y = fmaf(a4.z, w4.y, acc[2].y);
            acc[2].z = fmaf(a4.z, w4.z, acc[2].z); acc[2].w = fmaf(a4.z, w4.w, acc[2].w);
            acc[3].x = fmaf(a4.w, w4.x, acc[3].x); acc[3].y = fmaf(a4.w, w4.y, acc[3].y);
            acc[3].z = fmaf(a4.w, w4.z, acc[3].z); acc[3].w = fmaf(a4.w, w4.w, acc[3].w);
        }
    }

    const float4 b1 = *(const float4*)(B1 + tx * 4);
    const float4 b2 = *(const float4*)(B2 + tx * 4);
    const float4 b3 = *(const float4*)(B3 + tx * 4);
    const float4 bias = make_float4(b1.x + b2.x + b3.x, b1.y + b2.y + b3.y,
                                    b1.z + b2.z + b3.z, b1.w + b2.w + b3.w);
    #pragma unroll
    for (int i = 0; i < 4; ++i) {
        const int n = n0 + ty * 4 + i;
        if (n < nNodes) {
            float4 r = make_float4(acc[i].x + bias.x, acc[i].y + bias.y,
                                   acc[i].z + bias.z, acc[i].w + bias.w);
            r.x = r.x > 0.f ? r.x : 0.f;
            r.y = r.y > 0.f ? r.y : 0.f;
            r.z = r.z > 0.f ? r.z : 0.f;
            r.w = r.w > 0.f ? r.w : 0.f;
            *(float4*)(out + (size_t)n * 64 + tx * 4) = r;
        }
    }
}

extern "C" void kernel_launch(void* const* d_in, const int* in_sizes, int n_in,
                              void* d_out, int out_size, void* d_ws, size_t ws_size,
                              hipStream_t stream)
{
    const float* x    = (const float*)d_in[0];
    const int*   eidx = (const int*)d_in[1];
    const int*   ety  = (const int*)d_in[2];
    const int*   srcv = eidx;            // edge_index[0]
    const int*   dstv = eidx + NEDGES;   // edge_index[1]

    const float* wl0 = (const float*)d_in[3];
    const float* bl0 = (const float*)d_in[4];
    const float* w00 = (const float*)d_in[5];
    const float* b00 = (const float*)d_in[6];
    const float* w10 = (const float*)d_in[7];
    const float* b10 = (const float*)d_in[8];

    const float* wl1 = (const float*)d_in[9];
    const float* bl1 = (const float*)d_in[10];
    const float* w01 = (const float*)d_in[11];
    const float* b01 = (const float*)d_in[12];
    const float* w11 = (const float*)d_in[13];
    const float* b11 = (const float*)d_in[14];

    const float* wl2 = (const float*)d_in[15];
    const float* bl2 = (const float*)d_in[16];
    const float* w02 = (const float*)d_in[17];
    const float* b02 = (const float*)d_in[18];
    const float* w12 = (const float*)d_in[19];
    const float* b12 = (const float*)d_in[20];

    // ---- workspace layout (≈58.8 MB of d_ws) ----
    char* p = (char*)d_ws;
    auto alloc = [&](size_t bytes) {
        char* r = p;
        p += (bytes + 255) & ~(size_t)255;
        return r;
    };
    int* cnt  = (int*)alloc((size_t)RN * 4);
    int* off  = (int*)alloc((size_t)(RN + 1) * 4);
    int* wptr = (int*)alloc((size_t)RN * 4);
    int* bsum = (int*)alloc(1024);
    int* ebuf = (int*)alloc((size_t)NEDGES * 4);
    float* aggA = (float*)alloc((size_t)NNODES * 64 * sizeof(float));   // 25.6 MB
    float* aggB = (float*)alloc((size_t)NNODES * 64 * sizeof(float));   // 25.6 MB (contiguous after aggA)
    // layer0 agg = aggA..aggB as one [N,128]; layers 1/2: aggA = agg, aggB = h2
    float* h1 = (float*)d_out;

    const int edgeGrid = (NEDGES + 255) / 256;
    const int gemmGrid = (NNODES + 63) / 64;

    // ---- CSR build (once; serves all 3 relations) ----
    hipMemsetAsync(cnt, 0, (size_t)RN * 4, stream);
    hist_kernel<<<edgeGrid, 256, 0, stream>>>(srcv, ety, cnt);
    scan_reduce<<<SCAN_BLOCKS, 256, 0, stream>>>(cnt, bsum);
    scan_blocksums<<<1, 256, 0, stream>>>(bsum, SCAN_BLOCKS);
    scan_final<<<SCAN_BLOCKS, 256, 0, stream>>>(cnt, bsum, off, wptr);
    fill_kernel<<<edgeGrid, 256, 0, stream>>>(srcv, dstv, ety, wptr, ebuf);

    // ---- Layer 0: K = 128 (h = x = x_in) ----
    gather_kernel<128><<<4096, 256, 0, stream>>>(off, ebuf, x, aggA, 0);
    dense_gemm<128><<<gemmGrid, 256, 0, stream>>>(aggA, x, wl0, w00, w10,
                                                  bl0, b00, b10, h1, NNODES);

    // ---- Layer 1: K = 64 ----
    gather_kernel<64><<<4096, 256, 0, stream>>>(off, ebuf, h1, aggA, 1);
    dense_gemm<64><<<gemmGrid, 256, 0, stream>>>(aggA, h1, wl1, w01, w11,
                                                 bl1, b01, b11, aggB, NNODES);

    // ---- Layer 2: K = 64 (final output) ----
    gather_kernel<64><<<4096, 256, 0, stream>>>(off, ebuf, aggB, aggA, 2);
    dense_gemm<64><<<gemmGrid, 256, 0, stream>>>(aggA, aggB, wl2, w02, w12,
                                                 bl2, b02, b12, (float*)d_out, NNODES);
}